// Round 1
// baseline (778.752 us; speedup 1.0000x reference)
//
#include <hip/hip_runtime.h>

// SparseGlobalBroadcast: out[n][c] = in[n][c] + glob[batch_idx[n]][c]
// N = 1,000,000 points, C = 128 channels, B = 8 batches, fp32.
// Pure streaming memory-bound kernel: ~1.03 GB HBM traffic, ~163 us floor
// at 6.3 TB/s achievable.
//
// Layout: one thread per float4 (4 channels) => 32 float4 per point.
// Consecutive threads cover consecutive channel-quads => fully coalesced
// 16 B/lane loads & stores. Global feature table (8x128 fp32 = 4 KB) is
// staged into LDS once per block (256 float4 = exactly one load per thread).

#define C_VEC4 32            // 128 channels / 4 per float4
#define BLOCK 256

__global__ __launch_bounds__(BLOCK) void SparseGlobalBroadcast_54726473285929_kernel(
    const float4* __restrict__ in,        // [N * 32] float4
    const float4* __restrict__ glob,      // [B * 32] float4
    const int*    __restrict__ bidx,      // [N]
    float4*       __restrict__ out,       // [N * 32] float4
    int n_vec4) {
    __shared__ float4 sg[8 * C_VEC4];     // 4 KB: all B=8 global features

    const int t = threadIdx.x;
    // Stage global features: 8*32 = 256 float4, exactly one per thread.
    sg[t] = glob[t];
    __syncthreads();

    const int idx = blockIdx.x * BLOCK + t;
    if (idx < n_vec4) {
        const int point = idx >> 5;        // idx / 32
        const int c4    = idx & 31;        // channel-quad within point
        const int b     = bidx[point];     // broadcast across 32 threads
        const float4 a  = in[idx];
        const float4 g  = sg[(b << 5) + c4];
        out[idx] = make_float4(a.x + g.x, a.y + g.y, a.z + g.z, a.w + g.w);
    }
}

extern "C" void kernel_launch(void* const* d_in, const int* in_sizes, int n_in,
                              void* d_out, int out_size, void* d_ws, size_t ws_size,
                              hipStream_t stream) {
    const float4* in   = (const float4*)d_in[0];   // input_features  [N, 128] f32
    const float4* glob = (const float4*)d_in[1];   // input_features_global [8, 128] f32
    const int*    bidx = (const int*)d_in[2];      // batch_indices [N] i32
    float4*       out  = (float4*)d_out;

    const int n_vec4 = out_size / 4;               // N*128/4 = 32,000,000
    const int blocks = (n_vec4 + BLOCK - 1) / BLOCK;

    SparseGlobalBroadcast_54726473285929_kernel<<<blocks, BLOCK, 0, stream>>>(
        in, glob, bidx, out, n_vec4);
}